// Round 17
// baseline (502.616 us; speedup 1.0000x reference)
//
#include <hip/hip_runtime.h>

#define N_TOK 131072
#define KC    1024
#define DIM   256
#define GAP_THR 4e-4f
#define NBLK  (N_TOK / 128)      // 1024 token blocks

typedef __attribute__((ext_vector_type(8)))  short bf16x8;
typedef __attribute__((ext_vector_type(16))) float f32x16;

__device__ __forceinline__ unsigned short f2bf(float f) {
    unsigned int u = __float_as_uint(f);
    unsigned int r = (u + 0x7fffu + ((u >> 16) & 1u)) >> 16;   // RNE
    return (unsigned short)r;
}

// ================= ws layout =================
// 0       : cb16  (bf16)      524288 B   code-major [code][dim]
// 524288  : cnorm (f32)         4096 B
// 528384  : cbT   (f32)      1048576 B   cbT[d4][code][4] transposed codebook (recheck)
// 1576960 : fcounts (u32 x2)      64 B   [0]=pairs, [1]=rows
// 1577024 : flist2 (int)     4194304 B   entry = row | (blk << 17), one per pair
// 5771328 : flistR (int)      524288 B   flagged row ids (for fixup)
// 6295616 : rck   (u64)      1048576 B   per-row (dq_bits<<32 | code) atomicMin
// 7344192 : lparts (f64)        8192 B
#define WS_NEED 7352384ull

// cb -> bf16 (code-major) + cbT (fused transpose, d4 = lane) + f64 norms; zeroes counters
__global__ void vq_prep_cb(const float* __restrict__ cb, unsigned short* __restrict__ cb16,
                           float* __restrict__ cnorm, float* __restrict__ cbT,
                           unsigned int* __restrict__ fcounts) {
    if (blockIdx.x == 0 && threadIdx.x < 2) fcounts[threadIdx.x] = 0u;
    int code = blockIdx.x * 4 + (threadIdx.x >> 6);
    int lane = threadIdx.x & 63;
    float4 v = ((const float4*)cb)[(size_t)code * 64 + lane];
    ((float4*)cbT)[(size_t)lane * KC + code] = v;        // fused transpose
    ushort4 h;
    h.x = f2bf(v.x); h.y = f2bf(v.y); h.z = f2bf(v.z); h.w = f2bf(v.w);
    ((ushort4*)cb16)[(size_t)code * 64 + lane] = h;
    double s = 0.0;
    s = fma((double)v.x, (double)v.x, s);
    s = fma((double)v.y, (double)v.y, s);
    s = fma((double)v.z, (double)v.z, s);
    s = fma((double)v.w, (double)v.w, s);
    #pragma unroll
    for (int off = 32; off > 0; off >>= 1) s += __shfl_xor(s, off);
    if (lane == 0) cnorm[code] = (float)s;
}

// ---- Fused: bf16 MFMA scores over ALL 1024 codes + argmin/top-2 + flagging
//      + z_st output + loss partial. One pass over z (HBM) per block.
// Block: 256 thr = 4 waves (2 wcode x 2 wtok); per wave 64 codes x 64 tokens per cbk.
// B (tokens) register-resident: bfr[f][kb][ks]; A (codes) staged per cbk in 64KB
// swizzled LDS. Changes vs R16 (same MFMA/staging core): separate merge scratch
// (2 barriers/cbk not 3), single-pass top-2+argmin (no equality re-scan / acc
// writeback), f32 inner loss, pair+row emission fused into the flag phase.
__global__ __launch_bounds__(256)
void vq_scores_fused(const float* __restrict__ z, const unsigned short* __restrict__ cb16,
                     const float* __restrict__ cb, const float* __restrict__ cnorm,
                     float* __restrict__ out, float* __restrict__ out_idx,
                     int* __restrict__ flist2, int* __restrict__ flistR,
                     unsigned int* __restrict__ fcounts,
                     unsigned long long* __restrict__ rck, double* __restrict__ lparts)
{
    __shared__ uint4  cA[128 * 32];     // 64 KB : 128 codes x 256 dims bf16, 16B-unit swizzled
    __shared__ float  cnsL[KC];         // 4 KB
    __shared__ float  bm1L[8][128];     // per-cbk per-token block-min
    __shared__ float  gm1[128], gm2[128];
    __shared__ int    gid[128];
    __shared__ float  sm1s[256], sm2s[256];   // separate merge scratch (no cA alias)
    __shared__ int    sids[256];
    __shared__ double sredD[4];

    const int tid = threadIdx.x;
    const int lane = tid & 63;
    const int l31 = lane & 31;
    const int hi  = lane >> 5;
    const int wid = tid >> 6;
    const int wcode = wid >> 1;
    const int wtok  = wid & 1;
    const int tb = blockIdx.x;

    #pragma unroll
    for (int k = 0; k < 4; ++k) cnsL[tid + k * 256] = cnorm[tid + k * 256];
    if (tid < 128) { gm1[tid] = 3.0e38f; gm2[tid] = 3.0e38f; gid[tid] = 0x7fffffff; }

    // ---- B fragments from global f32 (lane hi-pairs consume full 64B lines) + zz ----
    bf16x8 bfr[2][4][4];
    float zzr[2];
    #pragma unroll
    for (int f = 0; f < 2; ++f) {
        const int t = tb * 128 + wtok * 64 + f * 32 + l31;
        const float* zr = z + (size_t)t * DIM;
        double s = 0.0;
        #pragma unroll
        for (int kb = 0; kb < 4; ++kb)
            #pragma unroll
            for (int ks = 0; ks < 4; ++ks) {
                const int d0 = kb * 64 + ks * 16 + hi * 8;
                float4 x = *(const float4*)(zr + d0);
                float4 y = *(const float4*)(zr + d0 + 4);
                s = fma((double)x.x, (double)x.x, s);
                s = fma((double)x.y, (double)x.y, s);
                s = fma((double)x.z, (double)x.z, s);
                s = fma((double)x.w, (double)x.w, s);
                s = fma((double)y.x, (double)y.x, s);
                s = fma((double)y.y, (double)y.y, s);
                s = fma((double)y.z, (double)y.z, s);
                s = fma((double)y.w, (double)y.w, s);
                bf16x8 v;
                v[0] = (short)f2bf(x.x); v[1] = (short)f2bf(x.y);
                v[2] = (short)f2bf(x.z); v[3] = (short)f2bf(x.w);
                v[4] = (short)f2bf(y.x); v[5] = (short)f2bf(y.y);
                v[6] = (short)f2bf(y.z); v[7] = (short)f2bf(y.w);
                bfr[f][kb][ks] = v;
            }
        s += __shfl_xor(s, 32);          // partner lane holds the other dim-half
        zzr[f] = (float)s;               // uniform per-row shift: argmin-invariant
    }

    // ---- loop all 8 code blocks (2 barriers per iteration) ----
    #pragma unroll 1
    for (int cbk = 0; cbk < 8; ++cbk) {
        #pragma unroll
        for (int i = 0; i < 16; ++i) {   // stage 64 KB code tile, swizzled 16B units
            int g = tid + i * 256;
            int c = g >> 5, u = g & 31;
            cA[c * 32 + (u ^ (c & 7))] = ((const uint4*)cb16)[(size_t)(cbk * 128 + c) * 32 + u];
        }
        __syncthreads();                 // A: stage done; prev merge done; iter0 init done

        f32x16 acc[2][2];
        #pragma unroll
        for (int a = 0; a < 2; ++a)
            #pragma unroll
            for (int b = 0; b < 2; ++b)
                #pragma unroll
                for (int r = 0; r < 16; ++r) acc[a][b][r] = 0.0f;

        #pragma unroll
        for (int kb = 0; kb < 4; ++kb)
            #pragma unroll
            for (int ks = 0; ks < 4; ++ks) {
                bf16x8 af[2];
                #pragma unroll
                for (int a = 0; a < 2; ++a) {
                    int c = wcode * 64 + a * 32 + l31;
                    af[a] = ((const bf16x8*)cA)[c * 32 + ((kb * 8 + ks * 2 + hi) ^ (c & 7))];
                }
                #pragma unroll
                for (int a = 0; a < 2; ++a)
                    #pragma unroll
                    for (int b = 0; b < 2; ++b)
                        acc[a][b] = __builtin_amdgcn_mfma_f32_32x32x16_bf16(af[a], bfr[b][kb][ks], acc[a][b], 0, 0, 0);
            }

        // epilogue: SINGLE-PASS top-2 + argmin over 32 codes (scan order is
        // code-monotone; strict < keeps lowest code on exact ties -> same
        // semantics as the old equality re-scan), then lane^32 merge.
        #pragma unroll
        for (int tf = 0; tf < 2; ++tf) {
            float c1 = 3.0e38f, c2 = 3.0e38f;
            int rl = 0;
            #pragma unroll
            for (int cf = 0; cf < 2; ++cf)
                #pragma unroll
                for (int r = 0; r < 16; ++r) {
                    int rc = cf * 32 + (r & 3) + 8 * (r >> 2);           // local code - 4*hi
                    float A  = zzr[tf] + cnsL[cbk * 128 + wcode * 64 + rc + 4 * hi];
                    float dq = fmaf(acc[cf][tf][r], -2.0f, A);           // fl(A - fl(2e))
                    bool lt = dq < c1;
                    c2 = fminf(c2, lt ? c1 : dq);                        // dup minima -> gap 0
                    rl = lt ? rc : rl;
                    c1 = lt ? dq : c1;
                }
            int ci = cbk * 128 + wcode * 64 + rl + 4 * hi;
            float o1 = __shfl_xor(c1, 32);
            float o2 = __shfl_xor(c2, 32);
            int  oi = __shfl_xor(ci, 32);
            float nm2 = fminf(fminf(c2, o2), fmaxf(c1, o1));
            int  ni = (o1 < c1 || (o1 == c1 && oi < ci)) ? oi : ci;
            float nm1 = fminf(c1, o1);
            if (hi == 0) {
                int lts = wtok * 64 + tf * 32 + l31;
                sm1s[wcode * 128 + lts] = nm1;
                sm2s[wcode * 128 + lts] = nm2;
                sids[wcode * 128 + lts] = ni;
            }
        }
        __syncthreads();                 // B: scratch ready + all cA reads done
        if (tid < 128) {                 // merge wcode halves + update running state
            float a1 = sm1s[tid],       a2 = sm2s[tid];       int ai = sids[tid];
            float b1 = sm1s[128 + tid], b2 = sm2s[128 + tid]; int bi = sids[128 + tid];
            float m1, m2; int ix;
            if (b1 < a1 || (b1 == a1 && bi < ai)) { m1 = b1; ix = bi; m2 = fminf(b2, a1); }
            else                                   { m1 = a1; ix = ai; m2 = fminf(a2, b1); }
            bm1L[cbk][tid] = m1;
            float g1 = gm1[tid], g2 = gm2[tid]; int gi = gid[tid];
            float ng2 = fminf(fminf(g2, m2), fmaxf(g1, m1));
            if (m1 < g1 || (m1 == g1 && ix < gi)) { g1 = m1; gi = ix; }
            gm1[tid] = g1; gm2[tid] = ng2; gid[tid] = gi;
        }
        // next iteration's stage overlaps the merge (disjoint LDS)
    }
    __syncthreads();

    // ---- flag: emit pairs + row-list + rck seed; provisional index write ----
    if (tid < 128) {
        int row = tb * 128 + tid;
        out_idx[row] = (float)gid[tid];
        float g1 = gm1[tid];
        float gap = gm2[tid] - g1;
        if (!(gap > GAP_THR)) {           // near-tie or NaN safety -> exact recheck
            rck[row] = ~0ull;
            unsigned int rp = atomicAdd(fcounts + 1, 1u);
            flistR[rp] = row;
            #pragma unroll
            for (int c = 0; c < 8; ++c)
                if (bm1L[c][tid] <= g1 + GAP_THR) {
                    unsigned int p = atomicAdd(fcounts, 1u);
                    flist2[p] = row | (c << 17);
                }
        }
    }

    // ---- fused z_st + loss (z tile re-read is L2-hot); f32 inner accumulation ----
    double ls = 0.0;
    const float4* z4  = (const float4*)z;
    const float4* cb4 = (const float4*)cb;
    float4* out4 = (float4*)out;
    #pragma unroll 4
    for (int it = 0; it < 32; ++it) {
        int fi = tid + it * 256;
        int row = fi >> 6, c4 = fi & 63;
        float4 zv = z4[(size_t)(tb * 128 + row) * 64 + c4];
        int idx = gid[row];
        float4 cv = cb4[(size_t)idx * 64 + c4];
        float4 o;
        o.x = zv.x + (cv.x - zv.x);
        o.y = zv.y + (cv.y - zv.y);
        o.z = zv.z + (cv.z - zv.z);
        o.w = zv.w + (cv.w - zv.w);
        out4[(size_t)(tb * 128 + row) * 64 + c4] = o;
        float dx = zv.x - cv.x, dy = zv.y - cv.y, dz = zv.z - cv.z, dw = zv.w - cv.w;
        float p4 = fmaf(dx, dx, fmaf(dy, dy, fmaf(dz, dz, dw * dw)));
        ls += (double)p4;                // f64 only at the per-float4 add (loss thr = 2%)
    }
    #pragma unroll
    for (int off = 32; off > 0; off >>= 1) ls += __shfl_down(ls, off);
    if (lane == 0) sredD[wid] = ls;
    __syncthreads();
    if (tid == 0) lparts[tb] = (sredD[0] + sredD[1]) + (sredD[2] + sredD[3]);
}

// ---- exact np-f32-chain recheck: ONE WAVE PER (row, block) PAIR, no barriers. ----
__global__ __launch_bounds__(256)
void vq_recheck_pairs(const float* __restrict__ z, const float* __restrict__ cbT,
                      const float* __restrict__ cnorm, const int* __restrict__ flist2,
                      const unsigned int* __restrict__ fcounts,
                      unsigned long long* __restrict__ rck)
{
    const int tid  = threadIdx.x;
    const int wid  = tid >> 6;
    const int lane = tid & 63;
    const unsigned int cnt = fcounts[0];

    for (unsigned int p = blockIdx.x * 4 + wid; p < cnt; p += gridDim.x * 4) {
        const int e   = flist2[p];
        const int row = e & 0x1FFFF;
        const int blk = ((unsigned int)e) >> 17;
        const float* zr = z + (size_t)row * DIM;

        float4 zv = ((const float4*)zr)[lane];
        double s = 0.0;
        s = fma((double)zv.x, (double)zv.x, s);
        s = fma((double)zv.y, (double)zv.y, s);
        s = fma((double)zv.z, (double)zv.z, s);
        s = fma((double)zv.w, (double)zv.w, s);
        #pragma unroll
        for (int off = 32; off > 0; off >>= 1) s += __shfl_xor(s, off);
        const float zz = (float)s;

        const int c0 = blk * 128 + lane;        // lane's two codes (c0 < c0+64)
        float e0 = 0.0f, e1 = 0.0f;
        #pragma unroll 8
        for (int d4 = 0; d4 < 64; ++d4) {       // strict sequential k = 0..255
            float4 zq = ((const float4*)zr)[d4];             // wave-uniform, L1-hot
            float4 a  = ((const float4*)cbT)[d4 * KC + c0];  // coalesced over lanes
            float4 b  = ((const float4*)cbT)[d4 * KC + c0 + 64];
            e0 = fmaf(zq.x, a.x, e0); e0 = fmaf(zq.y, a.y, e0);
            e0 = fmaf(zq.z, a.z, e0); e0 = fmaf(zq.w, a.w, e0);
            e1 = fmaf(zq.x, b.x, e1); e1 = fmaf(zq.y, b.y, e1);
            e1 = fmaf(zq.z, b.z, e1); e1 = fmaf(zq.w, b.w, e1);
        }
        const float dq0 = fmaf(e0, -2.0f, zz + cnorm[c0]);       // fl(fl(zz+cc) - fl(2e))
        const float dq1 = fmaf(e1, -2.0f, zz + cnorm[c0 + 64]);
        unsigned long long k0 = ((unsigned long long)__float_as_uint(dq0) << 32) | (unsigned int)c0;
        unsigned long long k1 = ((unsigned long long)__float_as_uint(dq1) << 32) | (unsigned int)(c0 + 64);
        unsigned long long k = k0 < k1 ? k0 : k1;
        #pragma unroll
        for (int off = 32; off > 0; off >>= 1) {
            unsigned long long o = __shfl_xor(k, off);
            k = o < k ? o : k;
        }
        if (lane == 0) atomicMin(&rck[row], k);
    }
}

// ---- fixup: one wave per flagged ROW: final idx + z_st row rewrite ----
__global__ __launch_bounds__(256)
void vq_fixup(const float* __restrict__ z, const float* __restrict__ cb,
              const int* __restrict__ flistR, const unsigned int* __restrict__ fcounts,
              const unsigned long long* __restrict__ rck,
              float* __restrict__ out, float* __restrict__ out_idx)
{
    const int tid  = threadIdx.x;
    const int wid  = tid >> 6;
    const int lane = tid & 63;
    const unsigned int cnt = fcounts[1];

    for (unsigned int p = blockIdx.x * 4 + wid; p < cnt; p += gridDim.x * 4) {
        const int row  = flistR[p];
        const int code = (int)(unsigned int)rck[row];   // low 32 bits = winning code
        float4 zv = ((const float4*)z)[(size_t)row * 64 + lane];
        float4 cv = ((const float4*)cb)[(size_t)code * 64 + lane];
        float4 o;
        o.x = zv.x + (cv.x - zv.x);
        o.y = zv.y + (cv.y - zv.y);
        o.z = zv.z + (cv.z - zv.z);
        o.w = zv.w + (cv.w - zv.w);
        ((float4*)out)[(size_t)row * 64 + lane] = o;
        if (lane == 0) out_idx[row] = (float)code;
    }
}

__global__ void vq_loss_final(const double* __restrict__ lparts, float* __restrict__ out_loss) {
    __shared__ double s[256];
    const int tid = threadIdx.x;
    double a = 0.0;
    for (int i = tid; i < NBLK; i += 256) a += lparts[i];
    s[tid] = a;
    __syncthreads();
    for (int sft = 128; sft > 0; sft >>= 1) {
        if (tid < sft) s[tid] += s[tid + sft];
        __syncthreads();
    }
    if (tid == 0) {
        float mean = (float)(s[0] / (double)((size_t)N_TOK * DIM));
        out_loss[0] = 0.25f * mean + mean;   // commit + codebook, reference op order
    }
}

extern "C" void kernel_launch(void* const* d_in, const int* in_sizes, int n_in,
                              void* d_out, int out_size, void* d_ws, size_t ws_size,
                              hipStream_t stream) {
    const float* z  = (const float*)d_in[0];
    const float* cb = (const float*)d_in[1];
    float* out = (float*)d_out;
    char* ws = (char*)d_ws;

    unsigned short*     cb16    = (unsigned short*)(ws);
    float*              cnorm   = (float*)(ws + 524288);
    float*              cbT     = (float*)(ws + 528384);
    unsigned int*       fcounts = (unsigned int*)(ws + 1576960);   // [0]=pairs, [1]=rows
    int*                flist2  = (int*)(ws + 1577024);
    int*                flistR  = (int*)(ws + 5771328);
    unsigned long long* rck     = (unsigned long long*)(ws + 6295616);
    double*             lparts  = (double*)(ws + 7344192);

    float* out_idx  = out + (size_t)N_TOK * DIM;
    float* out_loss = out_idx + N_TOK;

    vq_prep_cb<<<KC / 4, 256, 0, stream>>>(cb, cb16, cnorm, cbT, fcounts);
    vq_scores_fused<<<NBLK, 256, 0, stream>>>(z, cb16, cb, cnorm, out, out_idx,
                                              flist2, flistR, fcounts, rck, lparts);
    vq_recheck_pairs<<<2048, 256, 0, stream>>>(z, cbT, cnorm, flist2, fcounts, rck);
    vq_fixup<<<1024, 256, 0, stream>>>(z, cb, flistR, fcounts, rck, out, out_idx);
    vq_loss_final<<<1, 256, 0, stream>>>(lparts, out_loss);
}

// Round 18
// 326.433 us; speedup vs baseline: 1.5397x; 1.5397x over previous
//
#include <hip/hip_runtime.h>

#define N_TOK 131072
#define KC    1024
#define DIM   256
#define GAP_THR 4e-4f
#define NBLK  (N_TOK / 128)      // 1024 token blocks

typedef __attribute__((ext_vector_type(8)))  short bf16x8;
typedef __attribute__((ext_vector_type(16))) float f32x16;

__device__ __forceinline__ unsigned short f2bf(float f) {
    unsigned int u = __float_as_uint(f);
    unsigned int r = (u + 0x7fffu + ((u >> 16) & 1u)) >> 16;   // RNE
    return (unsigned short)r;
}

// ================= ws layout =================
// 0       : cb16  (bf16)      524288 B   code-major [code][dim]
// 524288  : cnorm (f32)         4096 B
// 528384  : cbT   (f32)      1048576 B   cbT[d4][code][4] transposed codebook (recheck)
// 1576960 : fcounts (u32 x2)      64 B   [0]=fcount (rows), [1]=fcount2 (pairs)
// 1577024 : flist (int)       524288 B   entry = row | (mask << 17), one per flagged row
// 2101312 : flist2 (int)     4194304 B   entry = row | (blk << 17), one per pair
// 6295616 : rck   (u64)      1048576 B   per-row (dq_bits<<32 | code) atomicMin
// 7344192 : lparts (f64)        8192 B
#define WS_NEED 7352384ull

// cb -> bf16 (code-major) + cbT (fused transpose, d4 = lane) + f64 norms; zeroes counters
__global__ void vq_prep_cb(const float* __restrict__ cb, unsigned short* __restrict__ cb16,
                           float* __restrict__ cnorm, float* __restrict__ cbT,
                           unsigned int* __restrict__ fcounts) {
    if (blockIdx.x == 0 && threadIdx.x < 2) fcounts[threadIdx.x] = 0u;
    int code = blockIdx.x * 4 + (threadIdx.x >> 6);
    int lane = threadIdx.x & 63;
    float4 v = ((const float4*)cb)[(size_t)code * 64 + lane];
    ((float4*)cbT)[(size_t)lane * KC + code] = v;        // fused transpose
    ushort4 h;
    h.x = f2bf(v.x); h.y = f2bf(v.y); h.z = f2bf(v.z); h.w = f2bf(v.w);
    ((ushort4*)cb16)[(size_t)code * 64 + lane] = h;
    double s = 0.0;
    s = fma((double)v.x, (double)v.x, s);
    s = fma((double)v.y, (double)v.y, s);
    s = fma((double)v.z, (double)v.z, s);
    s = fma((double)v.w, (double)v.w, s);
    #pragma unroll
    for (int off = 32; off > 0; off >>= 1) s += __shfl_xor(s, off);
    if (lane == 0) cnorm[code] = (float)s;
}

// ---- Fused: bf16 MFMA scores over ALL 1024 codes + argmin/top-2 + flagging
//      + z_st output + loss partial. One pass over z (HBM) per block.
// Block: 256 thr = 4 waves (2 wcode x 2 wtok); per wave 64 codes x 64 tokens per cbk.
// B (tokens) lives in registers for the whole kernel: bfr[f][kb][ks] bf16x8.
// A (codes) staged per cbk in 64KB swizzled LDS from L2-resident cb16.
// [R16-measured 232us compilation — byte-identical source, do not perturb.]
__global__ __launch_bounds__(256)
void vq_scores_fused(const float* __restrict__ z, const unsigned short* __restrict__ cb16,
                     const float* __restrict__ cb, const float* __restrict__ cnorm,
                     float* __restrict__ out, float* __restrict__ out_idx,
                     int* __restrict__ flist, unsigned int* __restrict__ fcount,
                     double* __restrict__ lparts)
{
    __shared__ uint4  cA[128 * 32];     // 64 KB : 128 codes x 256 dims bf16, 16B-unit swizzled
    __shared__ float  cnsL[KC];         // 4 KB
    __shared__ float  bm1L[8][128];     // per-cbk per-token block-min
    __shared__ float  gm1[128], gm2[128];
    __shared__ int    gid[128];
    __shared__ double sredD[4];

    const int tid = threadIdx.x;
    const int lane = tid & 63;
    const int l31 = lane & 31;
    const int hi  = lane >> 5;
    const int wid = tid >> 6;
    const int wcode = wid >> 1;
    const int wtok  = wid & 1;
    const int tb = blockIdx.x;

    #pragma unroll
    for (int k = 0; k < 4; ++k) cnsL[tid + k * 256] = cnorm[tid + k * 256];
    if (tid < 128) { gm1[tid] = 3.0e38f; gm2[tid] = 3.0e38f; gid[tid] = 0x7fffffff; }

    // ---- B fragments from global f32 (lane hi-pairs consume full 64B lines) + zz ----
    bf16x8 bfr[2][4][4];
    float zzr[2];
    #pragma unroll
    for (int f = 0; f < 2; ++f) {
        const int t = tb * 128 + wtok * 64 + f * 32 + l31;
        const float* zr = z + (size_t)t * DIM;
        double s = 0.0;
        #pragma unroll
        for (int kb = 0; kb < 4; ++kb)
            #pragma unroll
            for (int ks = 0; ks < 4; ++ks) {
                const int d0 = kb * 64 + ks * 16 + hi * 8;
                float4 x = *(const float4*)(zr + d0);
                float4 y = *(const float4*)(zr + d0 + 4);
                s = fma((double)x.x, (double)x.x, s);
                s = fma((double)x.y, (double)x.y, s);
                s = fma((double)x.z, (double)x.z, s);
                s = fma((double)x.w, (double)x.w, s);
                s = fma((double)y.x, (double)y.x, s);
                s = fma((double)y.y, (double)y.y, s);
                s = fma((double)y.z, (double)y.z, s);
                s = fma((double)y.w, (double)y.w, s);
                bf16x8 v;
                v[0] = (short)f2bf(x.x); v[1] = (short)f2bf(x.y);
                v[2] = (short)f2bf(x.z); v[3] = (short)f2bf(x.w);
                v[4] = (short)f2bf(y.x); v[5] = (short)f2bf(y.y);
                v[6] = (short)f2bf(y.z); v[7] = (short)f2bf(y.w);
                bfr[f][kb][ks] = v;
            }
        s += __shfl_xor(s, 32);          // partner lane holds the other dim-half
        zzr[f] = (float)s;               // uniform per-row shift: argmin-invariant
    }

    // ---- loop all 8 code blocks ----
    #pragma unroll 1
    for (int cbk = 0; cbk < 8; ++cbk) {
        __syncthreads();                 // cA/scratch free; init visible on iter 0
        #pragma unroll
        for (int i = 0; i < 16; ++i) {   // stage 64 KB code tile, swizzled 16B units
            int g = tid + i * 256;
            int c = g >> 5, u = g & 31;
            cA[c * 32 + (u ^ (c & 7))] = ((const uint4*)cb16)[(size_t)(cbk * 128 + c) * 32 + u];
        }
        __syncthreads();

        f32x16 acc[2][2];
        #pragma unroll
        for (int a = 0; a < 2; ++a)
            #pragma unroll
            for (int b = 0; b < 2; ++b)
                #pragma unroll
                for (int r = 0; r < 16; ++r) acc[a][b][r] = 0.0f;

        #pragma unroll
        for (int kb = 0; kb < 4; ++kb)
            #pragma unroll
            for (int ks = 0; ks < 4; ++ks) {
                bf16x8 af[2];
                #pragma unroll
                for (int a = 0; a < 2; ++a) {
                    int c = wcode * 64 + a * 32 + l31;
                    af[a] = ((const bf16x8*)cA)[c * 32 + ((kb * 8 + ks * 2 + hi) ^ (c & 7))];
                }
                #pragma unroll
                for (int a = 0; a < 2; ++a)
                    #pragma unroll
                    for (int b = 0; b < 2; ++b)
                        acc[a][b] = __builtin_amdgcn_mfma_f32_32x32x16_bf16(af[a], bfr[b][kb][ks], acc[a][b], 0, 0, 0);
            }

        // epilogue: per-lane top-2 over 32 codes, lane^32 merge, stash to scratch
        float* sm1 = (float*)cA;                 // cA reusable until next stage
        float* sm2 = sm1 + 256;
        int*   sid = (int*)(sm2 + 256);
        #pragma unroll
        for (int tf = 0; tf < 2; ++tf) {
            float c1 = 3.0e38f, c2 = 3.0e38f;
            #pragma unroll
            for (int cf = 0; cf < 2; ++cf)
                #pragma unroll
                for (int r = 0; r < 16; ++r) {
                    int cl = wcode * 64 + cf * 32 + (r & 3) + 8 * (r >> 2) + 4 * hi;
                    float A  = zzr[tf] + cnsL[cbk * 128 + cl];     // fl(zz+cc)
                    float dq = fmaf(acc[cf][tf][r], -2.0f, A);     // fl(A - fl(2e))
                    acc[cf][tf][r] = dq;
                    float hv = fmaxf(c1, dq);
                    c1 = fminf(c1, dq);
                    c2 = fminf(c2, hv);
                }
            int ci = 0x7fffffff;
            #pragma unroll
            for (int cf = 0; cf < 2; ++cf)
                #pragma unroll
                for (int r = 0; r < 16; ++r) {
                    int code = cbk * 128 + wcode * 64 + cf * 32 + (r & 3) + 8 * (r >> 2) + 4 * hi;
                    ci = min(ci, (acc[cf][tf][r] == c1) ? code : 0x7fffffff);
                }
            float o1 = __shfl_xor(c1, 32);
            float o2 = __shfl_xor(c2, 32);
            int  oi = __shfl_xor(ci, 32);
            float nm2 = fminf(fminf(c2, o2), fmaxf(c1, o1));
            int  ni = (o1 < c1 || (o1 == c1 && oi < ci)) ? oi : ci;
            float nm1 = fminf(c1, o1);
            if (hi == 0) {
                int lt = wtok * 64 + tf * 32 + l31;
                sm1[wcode * 128 + lt] = nm1;
                sm2[wcode * 128 + lt] = nm2;
                sid[wcode * 128 + lt] = ni;
            }
        }
        __syncthreads();
        if (tid < 128) {                  // merge wcode halves + update running state
            float a1 = sm1[tid],       a2 = sm2[tid];       int ai = sid[tid];
            float b1 = sm1[128 + tid], b2 = sm2[128 + tid]; int bi = sid[128 + tid];
            float m1, m2; int ix;
            if (b1 < a1 || (b1 == a1 && bi < ai)) { m1 = b1; ix = bi; m2 = fminf(b2, a1); }
            else                                   { m1 = a1; ix = ai; m2 = fminf(a2, b1); }
            bm1L[cbk][tid] = m1;
            float g1 = gm1[tid], g2 = gm2[tid]; int gi = gid[tid];
            float ng2 = fminf(fminf(g2, m2), fmaxf(g1, m1));
            if (m1 < g1 || (m1 == g1 && ix < gi)) { g1 = m1; gi = ix; }
            gm1[tid] = g1; gm2[tid] = ng2; gid[tid] = gi;
        }
    }
    __syncthreads();

    // ---- flag + provisional index write (mask format; expansion happens downstream) ----
    if (tid < 128) {
        int row = tb * 128 + tid;
        out_idx[row] = (float)gid[tid];
        float g1 = gm1[tid];
        float gap = gm2[tid] - g1;
        int mask = 0;
        #pragma unroll
        for (int c = 0; c < 8; ++c) mask |= (bm1L[c][tid] <= g1 + GAP_THR) ? (1 << c) : 0;
        if (!(gap > GAP_THR)) {           // near-tie or NaN safety -> exact recheck
            unsigned int p = atomicAdd(fcount, 1u);
            flist[p] = row | (mask << 17);
        }
    }
    __syncthreads();

    // ---- fused z_st + loss (z tile re-read is L2-hot) ----
    double ls = 0.0;
    const float4* z4  = (const float4*)z;
    const float4* cb4 = (const float4*)cb;
    float4* out4 = (float4*)out;
    #pragma unroll 4
    for (int it = 0; it < 32; ++it) {
        int fi = tid + it * 256;
        int row = fi >> 6, c4 = fi & 63;
        float4 zv = z4[(size_t)(tb * 128 + row) * 64 + c4];
        int idx = gid[row];
        float4 cv = cb4[(size_t)idx * 64 + c4];
        float4 o;
        o.x = zv.x + (cv.x - zv.x);
        o.y = zv.y + (cv.y - zv.y);
        o.z = zv.z + (cv.z - zv.z);
        o.w = zv.w + (cv.w - zv.w);
        out4[(size_t)(tb * 128 + row) * 64 + c4] = o;
        float dx = zv.x - cv.x, dy = zv.y - cv.y, dz = zv.z - cv.z, dw = zv.w - cv.w;
        ls += (double)dx * dx + (double)dy * dy + (double)dz * dz + (double)dw * dw;
    }
    #pragma unroll
    for (int off = 32; off > 0; off >>= 1) ls += __shfl_down(ls, off);
    if (lane == 0) sredD[wid] = ls;
    __syncthreads();
    if (tid == 0) lparts[tb] = (sredD[0] + sredD[1]) + (sredD[2] + sredD[3]);
}

// ---- expand mask-entries into per-pair entries + seed rck (tiny) ----
__global__ void vq_expand(const int* __restrict__ flist, const unsigned int* __restrict__ fcount,
                          int* __restrict__ flist2, unsigned int* __restrict__ fcount2,
                          unsigned long long* __restrict__ rck)
{
    const unsigned int cnt = *fcount;
    for (unsigned int i = blockIdx.x * 256 + threadIdx.x; i < cnt; i += gridDim.x * 256) {
        int e = flist[i];
        int row  = e & 0x1FFFF;
        int mask = ((unsigned int)e) >> 17;
        rck[row] = ~0ull;
        while (mask) {
            int c = __ffs(mask) - 1;
            mask &= mask - 1;
            unsigned int p = atomicAdd(fcount2, 1u);
            flist2[p] = row | (c << 17);
        }
    }
}

// ---- exact np-f32-chain recheck: ONE WAVE PER (row, block) PAIR, no barriers. ----
__global__ __launch_bounds__(256)
void vq_recheck_pairs(const float* __restrict__ z, const float* __restrict__ cbT,
                      const float* __restrict__ cnorm, const int* __restrict__ flist2,
                      const unsigned int* __restrict__ fcount2,
                      unsigned long long* __restrict__ rck)
{
    const int tid  = threadIdx.x;
    const int wid  = tid >> 6;
    const int lane = tid & 63;
    const unsigned int cnt = *fcount2;

    for (unsigned int p = blockIdx.x * 4 + wid; p < cnt; p += gridDim.x * 4) {
        const int e   = flist2[p];
        const int row = e & 0x1FFFF;
        const int blk = ((unsigned int)e) >> 17;
        const float* zr = z + (size_t)row * DIM;

        float4 zv = ((const float4*)zr)[lane];
        double s = 0.0;
        s = fma((double)zv.x, (double)zv.x, s);
        s = fma((double)zv.y, (double)zv.y, s);
        s = fma((double)zv.z, (double)zv.z, s);
        s = fma((double)zv.w, (double)zv.w, s);
        #pragma unroll
        for (int off = 32; off > 0; off >>= 1) s += __shfl_xor(s, off);
        const float zz = (float)s;

        const int c0 = blk * 128 + lane;        // lane's two codes (c0 < c0+64)
        float e0 = 0.0f, e1 = 0.0f;
        #pragma unroll 8
        for (int d4 = 0; d4 < 64; ++d4) {       // strict sequential k = 0..255
            float4 zq = ((const float4*)zr)[d4];             // wave-uniform, L1-hot
            float4 a  = ((const float4*)cbT)[d4 * KC + c0];  // coalesced over lanes
            float4 b  = ((const float4*)cbT)[d4 * KC + c0 + 64];
            e0 = fmaf(zq.x, a.x, e0); e0 = fmaf(zq.y, a.y, e0);
            e0 = fmaf(zq.z, a.z, e0); e0 = fmaf(zq.w, a.w, e0);
            e1 = fmaf(zq.x, b.x, e1); e1 = fmaf(zq.y, b.y, e1);
            e1 = fmaf(zq.z, b.z, e1); e1 = fmaf(zq.w, b.w, e1);
        }
        const float dq0 = fmaf(e0, -2.0f, zz + cnorm[c0]);       // fl(fl(zz+cc) - fl(2e))
        const float dq1 = fmaf(e1, -2.0f, zz + cnorm[c0 + 64]);
        unsigned long long k0 = ((unsigned long long)__float_as_uint(dq0) << 32) | (unsigned int)c0;
        unsigned long long k1 = ((unsigned long long)__float_as_uint(dq1) << 32) | (unsigned int)(c0 + 64);
        unsigned long long k = k0 < k1 ? k0 : k1;
        #pragma unroll
        for (int off = 32; off > 0; off >>= 1) {
            unsigned long long o = __shfl_xor(k, off);
            k = o < k ? o : k;
        }
        if (lane == 0) atomicMin(&rck[row], k);
    }
}

// ---- fixup: one wave per pair (duplicates idempotent): final idx + z_st row rewrite
__global__ __launch_bounds__(256)
void vq_fixup(const float* __restrict__ z, const float* __restrict__ cb,
              const int* __restrict__ flist2, const unsigned int* __restrict__ fcount2,
              const unsigned long long* __restrict__ rck,
              float* __restrict__ out, float* __restrict__ out_idx)
{
    const int tid  = threadIdx.x;
    const int wid  = tid >> 6;
    const int lane = tid & 63;
    const unsigned int cnt = *fcount2;

    for (unsigned int p = blockIdx.x * 4 + wid; p < cnt; p += gridDim.x * 4) {
        const int row  = flist2[p] & 0x1FFFF;
        const int code = (int)(unsigned int)rck[row];   // low 32 bits = winning code
        float4 zv = ((const float4*)z)[(size_t)row * 64 + lane];
        float4 cv = ((const float4*)cb)[(size_t)code * 64 + lane];
        float4 o;
        o.x = zv.x + (cv.x - zv.x);
        o.y = zv.y + (cv.y - zv.y);
        o.z = zv.z + (cv.z - zv.z);
        o.w = zv.w + (cv.w - zv.w);
        ((float4*)out)[(size_t)row * 64 + lane] = o;
        if (lane == 0) out_idx[row] = (float)code;
    }
}

__global__ void vq_loss_final(const double* __restrict__ lparts, float* __restrict__ out_loss) {
    __shared__ double s[256];
    const int tid = threadIdx.x;
    double a = 0.0;
    for (int i = tid; i < NBLK; i += 256) a += lparts[i];
    s[tid] = a;
    __syncthreads();
    for (int sft = 128; sft > 0; sft >>= 1) {
        if (tid < sft) s[tid] += s[tid + sft];
        __syncthreads();
    }
    if (tid == 0) {
        float mean = (float)(s[0] / (double)((size_t)N_TOK * DIM));
        out_loss[0] = 0.25f * mean + mean;   // commit + codebook, reference op order
    }
}

extern "C" void kernel_launch(void* const* d_in, const int* in_sizes, int n_in,
                              void* d_out, int out_size, void* d_ws, size_t ws_size,
                              hipStream_t stream) {
    const float* z  = (const float*)d_in[0];
    const float* cb = (const float*)d_in[1];
    float* out = (float*)d_out;
    char* ws = (char*)d_ws;

    unsigned short*     cb16    = (unsigned short*)(ws);
    float*              cnorm   = (float*)(ws + 524288);
    float*              cbT     = (float*)(ws + 528384);
    unsigned int*       fcounts = (unsigned int*)(ws + 1576960);   // [0]=rows, [1]=pairs
    int*                flist   = (int*)(ws + 1577024);
    int*                flist2  = (int*)(ws + 2101312);
    unsigned long long* rck     = (unsigned long long*)(ws + 6295616);
    double*             lparts  = (double*)(ws + 7344192);

    float* out_idx  = out + (size_t)N_TOK * DIM;
    float* out_loss = out_idx + N_TOK;

    vq_prep_cb<<<KC / 4, 256, 0, stream>>>(cb, cb16, cnorm, cbT, fcounts);
    vq_scores_fused<<<NBLK, 256, 0, stream>>>(z, cb16, cb, cnorm, out, out_idx,
                                              flist, fcounts, lparts);
    vq_expand<<<64, 256, 0, stream>>>(flist, fcounts, flist2, fcounts + 1, rck);
    vq_recheck_pairs<<<2048, 256, 0, stream>>>(z, cbT, cnorm, flist2, fcounts + 1, rck);
    vq_fixup<<<1024, 256, 0, stream>>>(z, cb, flist2, fcounts + 1, rck, out, out_idx);
    vq_loss_final<<<1, 256, 0, stream>>>(lparts, out_loss);
}